// Round 8
// baseline (1227.320 us; speedup 1.0000x reference)
//
#include <hip/hip_runtime.h>

// R15 DIAGNOSTIC v2. R13's probes were CSE'd (pure builtin loads, same
// addresses re-swept, 64 holdable VGPRs) -> measured one sweep, invisible,
// discriminated nothing. This round makes the REAL kernel visible in top-5:
//   gemv10 : R11's kernel x10 reps in-dispatch (~1 ms -> top-5 row with
//            hbm_gbps/FETCH/VALUBusy/Occupancy). Idempotent: same out
//            rewritten each rep; per-rep prologue __syncthreads protects
//            LDS reuse. B=268MB > L3=256MB -> each rep ~cold.
//   loads10: R11's exact load cadence (same addresses, nt builtins, same
//            launch shape), consume replaced by asm keep-alive. 80 loads/rep
//            >= 320 VGPRs -> cross-rep CSE structurally impossible.
// Decision tree: (A) both ~3 TB/s -> address-mapping next / roofline.
// (B) loads10 >=5, gemv10 ~3 -> consume drags stream -> barrier-free consume.
// (C) both >=5 -> gemv near-roofline, fills dominate dur_us.
// (D) gemv10 FETCH >> 3 GB -> writeback/overfetch -> cache-policy attack.

#define TPB   512
#define ROWS  2
#define TILES 16
#define CROWS (ROWS * TILES)   // 32 rows per block
#define REPS  10

typedef int   ivec4 __attribute__((ext_vector_type(4)));
typedef float fvec2 __attribute__((ext_vector_type(2)));

// ------------------------------------------------------- gemv10 (R11 x10) --
__global__ __launch_bounds__(TPB, 4) void gemv10(
    const float4* __restrict__ A4,
    const ivec4*  __restrict__ B,
    const fvec2*  __restrict__ SZ,
    float* __restrict__ out,
    int N)
{
    const int t    = threadIdx.x;
    const int row0 = blockIdx.x * CROWS;
    const int g0   = t >> 2;

    __shared__ fvec2 sz_s[2][ROWS * 256];
    __shared__ float red[2][ROWS][TPB / 64];

    float a[2][8];
    float sA[2];
#pragma unroll
    for (int j = 0; j < 2; ++j) {
        const int i = t + 512 * j;
        const float4 x = A4[2 * i];
        const float4 y = A4[2 * i + 1];
        a[j][0] = x.x; a[j][1] = x.y; a[j][2] = x.z; a[j][3] = x.w;
        a[j][4] = y.x; a[j][5] = y.y; a[j][6] = y.z; a[j][7] = y.w;
        sA[j] = ((x.x + x.y) + (x.z + x.w)) + ((y.x + y.y) + (y.z + y.w));
    }

    ivec4 bufA[ROWS][2], bufB[ROWS][2];
    fvec2 szrA, szrB;

    auto issue = [&](int T, ivec4 (&buf)[ROWS][2], fvec2& szr) {
        const int rt = row0 + T * ROWS;
        szr = __builtin_nontemporal_load(&SZ[(size_t)rt * 256 + t]);
        const ivec4* Bp = B + (size_t)rt * 1024 + t;
#pragma unroll
        for (int r = 0; r < ROWS; ++r)
#pragma unroll
            for (int j = 0; j < 2; ++j)
                buf[r][j] = __builtin_nontemporal_load(&Bp[r * 1024 + 512 * j]);
    };

    auto consume = [&](const ivec4 (&buf)[ROWS][2], const fvec2* szl,
                       float (&redb)[ROWS][TPB / 64]) {
        float acc[ROWS];
#pragma unroll
        for (int r = 0; r < ROWS; ++r) acc[r] = 0.0f;
#pragma unroll
        for (int r = 0; r < ROWS; ++r) {
#pragma unroll
            for (int j = 0; j < 2; ++j) {
                const fvec2 sz = szl[r * 256 + g0 + 128 * j];
                const int b0 = buf[r][j][0], b1 = buf[r][j][1];
                const int b2 = buf[r][j][2], b3 = buf[r][j][3];
                float dot = 0.0f;
                dot = fmaf(a[j][0], (float)(b0 & 0xF),        dot);
                dot = fmaf(a[j][1], (float)((b0 >> 4) & 0xF), dot);
                dot = fmaf(a[j][2], (float)(b1 & 0xF),        dot);
                dot = fmaf(a[j][3], (float)((b1 >> 4) & 0xF), dot);
                dot = fmaf(a[j][4], (float)(b2 & 0xF),        dot);
                dot = fmaf(a[j][5], (float)((b2 >> 4) & 0xF), dot);
                dot = fmaf(a[j][6], (float)(b3 & 0xF),        dot);
                dot = fmaf(a[j][7], (float)((b3 >> 4) & 0xF), dot);
                acc[r] = fmaf(sz[0], dot, acc[r]);
                acc[r] = fmaf(fmaf(-8.0f, sz[0], sz[1]), sA[j], acc[r]);
            }
        }
        const int lane = t & 63;
        const int w    = t >> 6;
#pragma unroll
        for (int r = 0; r < ROWS; ++r) {
            float v = acc[r];
#pragma unroll
            for (int off = 32; off > 0; off >>= 1)
                v += __shfl_down(v, off, 64);
            if (lane == 0) redb[r][w] = v;
        }
    };

    auto store2 = [&](int T, const float (&redb)[ROWS][TPB / 64]) {
        if (t < ROWS) {
            const int n = row0 + T * ROWS + t;
            if (n < N) {
                float v = 0.0f;
#pragma unroll
                for (int w2 = 0; w2 < TPB / 64; ++w2) v += redb[t][w2];
                out[n] = v;
            }
        }
    };

    for (int rep = 0; rep < REPS; ++rep) {
        issue(0, bufA, szrA);
        sz_s[0][t] = szrA;
        __syncthreads();                 // also fences prev rep's red reads

        for (int TT = 0; TT < TILES; TT += 2) {
            if (TT + 1 < TILES) issue(TT + 1, bufB, szrB);
            consume(bufA, &sz_s[0][0], red[0]);
            if (TT + 1 < TILES) sz_s[1][t] = szrB;
            __syncthreads();
            store2(TT, red[0]);

            if (TT + 2 < TILES) issue(TT + 2, bufA, szrA);
            consume(bufB, &sz_s[1][0], red[1]);
            if (TT + 2 < TILES) sz_s[0][t] = szrA;
            __syncthreads();
            store2(TT + 1, red[1]);
        }
    }
}

// ------------------------------------------------------------------ loads10 --
// R11's exact load stream (addresses, nt builtins, launch shape), zero
// consume. Keep-alives pin every loaded value (rule #17). 80 loads/rep
// per thread -> values can't all stay resident -> reps must re-load.
__global__ __launch_bounds__(TPB, 4) void loads10(
    const ivec4* __restrict__ B,
    const fvec2* __restrict__ SZ)
{
    const int t    = threadIdx.x;
    const int row0 = blockIdx.x * CROWS;

    ivec4 bA[4], bB[4];
    fvec2 sA_, sB_;

    auto issue = [&](int T, ivec4 (&buf)[4], fvec2& szr) {
        const int rt = row0 + T * ROWS;
        szr = __builtin_nontemporal_load(&SZ[(size_t)rt * 256 + t]);
        const ivec4* Bp = B + (size_t)rt * 1024 + t;
        buf[0] = __builtin_nontemporal_load(&Bp[0]);
        buf[1] = __builtin_nontemporal_load(&Bp[512]);
        buf[2] = __builtin_nontemporal_load(&Bp[1024]);
        buf[3] = __builtin_nontemporal_load(&Bp[1536]);
    };
    auto keep = [&](ivec4 (&buf)[4], fvec2& szr) {
        asm volatile("" :: "v"(buf[0]), "v"(buf[1]), "v"(buf[2]),
                           "v"(buf[3]), "v"(szr));
    };

    for (int rep = 0; rep < REPS; ++rep) {
        issue(0, bA, sA_);
        for (int TT = 0; TT < TILES; TT += 2) {
            if (TT + 1 < TILES) issue(TT + 1, bB, sB_);
            keep(bA, sA_);
            if (TT + 2 < TILES) issue(TT + 2, bA, sA_);
            keep(bB, sB_);
        }
    }
}

extern "C" void kernel_launch(void* const* d_in, const int* in_sizes, int n_in,
                              void* d_out, int out_size, void* d_ws, size_t ws_size,
                              hipStream_t stream) {
    const float4* A4 = (const float4*)d_in[0];   // f32[8192]
    const ivec4*  B  = (const ivec4*)d_in[1];    // int32[N, 4096]
    const fvec2*  SZ = (const fvec2*)d_in[2];    // f32[N, 256, 2]
    float* out = (float*)d_out;                  // f32[N]

    const int N = out_size;                      // 16384
    gemv10<<<N / CROWS, TPB, 0, stream>>>(A4, B, SZ, out, N);
    loads10<<<N / CROWS, TPB, 0, stream>>>(B, SZ);
}

// Round 9
// 350.835 us; speedup vs baseline: 3.4983x; 3.4983x over previous
//
#include <hip/hip_runtime.h>

// int4 weight-only quantized GEMV: out[n] = sum_k A[k] * W[n,k]
//   W[n,k] = (nib(B)[n,k] - 8) * scale[n, k/32] + zero[n, k/32]
// M=1, K=8192, N=16384, GROUP=32.
//
// R16: CHANNEL PHASE-HOTSPOT theory. R15 counters: loads-only at R11's shape
// caps at 3.4 TB/s HBM despite 224 KB/CU outstanding + 0.1% VALUBusy (not
// latency, not consume: gemv10 matched loads10); fills write through during
// their own dispatch (WRITE_SIZE == fill size) so no writeback tax. The one
// invariant across all six ~3 TB/s variants: every block streams a private
// CONTIGUOUS 512 KB region in lock-step phase -> if channel striping period
// divides 512 KB, all 512 blocks hit the same channel subset simultaneously
// (rotating hotspot). Chip-wide interleaved readers (RMSNorm 4.9, LN 5.2,
// fill 6.7 TB/s) don't do this. Fix = ONE variable: block b owns rows
// {b + s*gridDim}, s=0..31 (was: 32 contiguous rows). At any tile T all
// blocks collectively read a contiguous ~16 MB row window -> uniform
// channels. Pipeline/consume/occupancy identical to R11.

#define TPB   512
#define ROWS  2
#define TILES 16
#define CROWS (ROWS * TILES)   // 32 rows per block

typedef int   ivec4 __attribute__((ext_vector_type(4)));
typedef float fvec2 __attribute__((ext_vector_type(2)));

__global__ __launch_bounds__(TPB, 4) void gemv_w4il(
    const float4* __restrict__ A4,   // 8192 f32 = 2048 float4
    const ivec4*  __restrict__ B,    // [N, 1024] (16B = 4 int32 = 8 k)
    const fvec2*  __restrict__ SZ,   // [N, 256] (scale, zero) f32 pairs
    float* __restrict__ out,         // [N] f32
    int N)
{
    const int t      = threadIdx.x;
    const int b      = blockIdx.x;
    const int stride = gridDim.x;     // 512: row for slot s is b + s*stride
    const int g0     = t >> 2;

    __shared__ fvec2 sz_s[2][ROWS * 256];
    __shared__ float red[2][ROWS][TPB / 64];

    // ---- A -> regs once (thread t covers ivec4 t and t+512 of every row) ---
    float a[2][8];
    float sA[2];
#pragma unroll
    for (int j = 0; j < 2; ++j) {
        const int i = t + 512 * j;
        const float4 x = A4[2 * i];
        const float4 y = A4[2 * i + 1];
        a[j][0] = x.x; a[j][1] = x.y; a[j][2] = x.z; a[j][3] = x.w;
        a[j][4] = y.x; a[j][5] = y.y; a[j][6] = y.z; a[j][7] = y.w;
        sA[j] = ((x.x + x.y) + (x.z + x.w)) + ((y.x + y.y) + (y.z + y.w));
    }

    ivec4 bufA[ROWS][2], bufB[ROWS][2];
    fvec2 szrA, szrB;

    // tile T covers rows n_r = b + (T*ROWS + r)*stride, r = 0..1
    auto issue = [&](int T, ivec4 (&buf)[ROWS][2], fvec2& szr) {
        // SZ: threads 0..255 load row (T*ROWS+0)'s 256 groups, 256..511 row +1
        const int rr = t >> 8;                    // 0 or 1
        const int gg = t & 255;
        const int ns = b + (T * ROWS + rr) * stride;
        szr = __builtin_nontemporal_load(&SZ[(size_t)ns * 256 + gg]);
#pragma unroll
        for (int r = 0; r < ROWS; ++r) {
            const int n = b + (T * ROWS + r) * stride;
            const ivec4* Bp = B + (size_t)n * 1024 + t;
#pragma unroll
            for (int j = 0; j < 2; ++j)
                buf[r][j] = __builtin_nontemporal_load(&Bp[512 * j]);
        }
    };

    auto consume = [&](const ivec4 (&buf)[ROWS][2], const fvec2* szl,
                       float (&redb)[ROWS][TPB / 64]) {
        float acc[ROWS];
#pragma unroll
        for (int r = 0; r < ROWS; ++r) acc[r] = 0.0f;
#pragma unroll
        for (int r = 0; r < ROWS; ++r) {
#pragma unroll
            for (int j = 0; j < 2; ++j) {
                const fvec2 sz = szl[r * 256 + g0 + 128 * j];
                const int b0 = buf[r][j][0], b1 = buf[r][j][1];
                const int b2 = buf[r][j][2], b3 = buf[r][j][3];
                float dot = 0.0f;
                dot = fmaf(a[j][0], (float)(b0 & 0xF),        dot);
                dot = fmaf(a[j][1], (float)((b0 >> 4) & 0xF), dot);
                dot = fmaf(a[j][2], (float)(b1 & 0xF),        dot);
                dot = fmaf(a[j][3], (float)((b1 >> 4) & 0xF), dot);
                dot = fmaf(a[j][4], (float)(b2 & 0xF),        dot);
                dot = fmaf(a[j][5], (float)((b2 >> 4) & 0xF), dot);
                dot = fmaf(a[j][6], (float)(b3 & 0xF),        dot);
                dot = fmaf(a[j][7], (float)((b3 >> 4) & 0xF), dot);
                acc[r] = fmaf(sz[0], dot, acc[r]);
                acc[r] = fmaf(fmaf(-8.0f, sz[0], sz[1]), sA[j], acc[r]);
            }
        }
        const int lane = t & 63;
        const int w    = t >> 6;
#pragma unroll
        for (int r = 0; r < ROWS; ++r) {
            float v = acc[r];
#pragma unroll
            for (int off = 32; off > 0; off >>= 1)
                v += __shfl_down(v, off, 64);
            if (lane == 0) redb[r][w] = v;
        }
    };

    auto store2 = [&](int T, const float (&redb)[ROWS][TPB / 64]) {
        if (t < ROWS) {
            const int n = b + (T * ROWS + t) * stride;
            if (n < N) {
                float v = 0.0f;
#pragma unroll
                for (int w2 = 0; w2 < TPB / 64; ++w2) v += redb[t][w2];
                out[n] = v;
            }
        }
    };

    issue(0, bufA, szrA);
    sz_s[0][t] = szrA;
    __syncthreads();

    for (int TT = 0; TT < TILES; TT += 2) {
        if (TT + 1 < TILES) issue(TT + 1, bufB, szrB);
        consume(bufA, &sz_s[0][0], red[0]);
        if (TT + 1 < TILES) sz_s[1][t] = szrB;
        __syncthreads();
        store2(TT, red[0]);

        if (TT + 2 < TILES) issue(TT + 2, bufA, szrA);
        consume(bufB, &sz_s[1][0], red[1]);
        if (TT + 2 < TILES) sz_s[0][t] = szrA;
        __syncthreads();
        store2(TT + 1, red[1]);
    }
}

extern "C" void kernel_launch(void* const* d_in, const int* in_sizes, int n_in,
                              void* d_out, int out_size, void* d_ws, size_t ws_size,
                              hipStream_t stream) {
    const float4* A4 = (const float4*)d_in[0];   // f32[8192]
    const ivec4*  B  = (const ivec4*)d_in[1];    // int32[N, 4096]
    const fvec2*  SZ = (const fvec2*)d_in[2];    // f32[N, 256, 2]
    float* out = (float*)d_out;                  // f32[N]

    const int N = out_size;                      // 16384
    gemv_w4il<<<N / CROWS, TPB, 0, stream>>>(A4, B, SZ, out, N);
}